// Round 6
// baseline (445.902 us; speedup 1.0000x reference)
//
#include <hip/hip_runtime.h>

#define NUM_CODES 1024
#define CODE_DIM  256
#define N_ROWS    32768

// output layout (floats)
#define ZQ_OFF    0
#define LOSS_OFF  8388608
#define IDX_OFF   8388609
#define CS_OFF    8421377
#define NEA_OFF   8422401
#define NORM_OFF  8684545

#define EMA       0.99f
#define ONE_M_EMA 0.01f
#define EPSF      1e-6f
#define LOSS_SCALE (0.25f / 8388608.0f)

// ws layout (bytes)
#define WS_N_B      0                     // float n
#define WS_ENORM_B  64                    // 1024 floats
#define WS_CNT_B    (WS_ENORM_B + 4096)   // 1024 uint counts
#define WS_EH_B     (WS_CNT_B + 4096)     // 512 KB E hi frag-major [plane][code][8]
#define WS_EL_B     (WS_EH_B + 524288)    // 512 KB E lo

typedef __attribute__((ext_vector_type(8))) short short8;
typedef __attribute__((ext_vector_type(4))) float f32x4;

__device__ __forceinline__ unsigned short f2bf(float x) {
  union { float f; unsigned u; } v; v.f = x;
  unsigned r = v.u + 0x7fffu + ((v.u >> 16) & 1u);
  return (unsigned short)(r >> 16);
}
__device__ __forceinline__ float bf2f(unsigned short b) {
  union { unsigned u; float f; } v; v.u = ((unsigned)b) << 16;
  return v.f;
}

// ---------------------------------------------------------------- K0: setup
// zero loss + counts + NEA accumulators; E split hi/lo frag-major; enorm
__global__ void k_setup(const float* __restrict__ emb, float* __restrict__ out,
                        float* __restrict__ wsf) {
  const int b = blockIdx.x, t = threadIdx.x;
  char* wsb = (char*)wsf;
  // zero NEA accumulator region (1024 blocks x 256 = 262144 floats)
  out[NEA_OFF + (long)b * 256 + t] = 0.0f;
  if (b < 4) ((unsigned*)(wsb + WS_CNT_B))[b * 256 + t] = 0u;
  if (b == 0 && t == 0) out[LOSS_OFF] = 0.0f;

  float x = emb[(long)b * CODE_DIM + t];
  unsigned short hb = f2bf(x);
  unsigned short lb = f2bf(x - bf2f(hb));
  unsigned short* eh = (unsigned short*)(wsb + WS_EH_B);
  unsigned short* el = (unsigned short*)(wsb + WS_EL_B);
  int p = t >> 3, j = t & 7;                 // plane = k/8, elem = k%8
  long eo = ((long)p * NUM_CODES + b) * 8 + j;
  eh[eo] = hb; el[eo] = lb;
  float v = x * x;
  #pragma unroll
  for (int o = 32; o >= 1; o >>= 1) v += __shfl_xor(v, o);
  __shared__ float s[4];
  if ((t & 63) == 0) s[t >> 6] = v;
  __syncthreads();
  if (t == 0) ((float*)(wsb + WS_ENORM_B))[b] = s[0] + s[1] + s[2] + s[3];
}

// ---------------------------------------------------------------- K1: main
// 128 thr (2 waves x 32 rows); reg-staged dbuf LDS (T14 async-split);
// chunk rotation per block; fused atomic epilogue.
#define BM        64
#define NC        32
#define NCHUNK    32
#define CHUNK_B   32768      // hi(16KB) + lo(16KB)

__launch_bounds__(128)
__global__ void k_main(const float* __restrict__ z, const float* __restrict__ emb,
                       float* __restrict__ wsf, float* __restrict__ out) {
  __shared__ __align__(16) unsigned char lds[2 * CHUNK_B];
  __shared__ int   s_idx[BM];
  __shared__ float s_l[2];

  const char* wsb = (const char*)wsf;
  const float* enp = (const float*)(wsb + WS_ENORM_B);
  const int tid = threadIdx.x;
  const int w   = tid >> 6;
  const int l   = tid & 63;
  const int mrow = l & 15;
  const int kq   = l >> 4;
  const int row0 = blockIdx.x * BM;
  const int rot  = blockIdx.x & 31;    // chunk rotation (L2 burst decorrelation)

  // ---- A: 32 rows per wave (2 mtiles), hi/lo bf16 fragments in registers
  short8 aH0[8], aL0[8], aH1[8], aL1[8];
  {
    const float* zr0 = z + (long)(row0 + w * 32 + mrow) * CODE_DIM + kq * 8;
    const float* zr1 = zr0 + 16 * CODE_DIM;
    #pragma unroll
    for (int ks = 0; ks < 8; ++ks) {
      float4 f0 = *(const float4*)(zr0 + ks * 32);
      float4 f1 = *(const float4*)(zr0 + ks * 32 + 4);
      float4 g0 = *(const float4*)(zr1 + ks * 32);
      float4 g1 = *(const float4*)(zr1 + ks * 32 + 4);
      float xs[8] = {f0.x, f0.y, f0.z, f0.w, f1.x, f1.y, f1.z, f1.w};
      float ys[8] = {g0.x, g0.y, g0.z, g0.w, g1.x, g1.y, g1.z, g1.w};
      #pragma unroll
      for (int j = 0; j < 8; ++j) {
        unsigned short hb = f2bf(xs[j]);
        aH0[ks][j] = (short)hb; aL0[ks][j] = (short)f2bf(xs[j] - bf2f(hb));
        unsigned short hc = f2bf(ys[j]);
        aH1[ks][j] = (short)hc; aL1[ks][j] = (short)f2bf(ys[j] - bf2f(hc));
      }
    }
  }

  // ---- reg-staged chunk pipeline: issue loads early, commit after barrier
  float4 stg[16];
  auto issue = [&](int chunk) {
    #pragma unroll
    for (int it = 0; it < 16; ++it) {
      int d  = (it * 128 + tid) * 16;
      int s  = d >> 14;
      int d2 = d & 16383;
      int p  = d2 >> 9;
      int in_ = d2 & 511;
      stg[it] = *(const float4*)(wsb + (s ? WS_EL_B : WS_EH_B) + p * 16384
                                 + chunk * 512 + in_);
    }
  };
  auto commit = [&](int buf) {
    #pragma unroll
    for (int it = 0; it < 16; ++it) {
      int d = (it * 128 + tid) * 16;
      *(float4*)(lds + buf * CHUNK_B + d) = stg[it];
    }
  };

  float best0[4], best1[4]; int bidx0[4], bidx1[4];
  #pragma unroll
  for (int r = 0; r < 4; ++r) {
    best0[r] = 3.0e38f; bidx0[r] = 0x7fffffff;
    best1[r] = 3.0e38f; bidx1[r] = 0x7fffffff;
  }

  issue((0 + rot) & 31);
  commit(0);
  __syncthreads();

  for (int ci = 0; ci < NCHUNK; ++ci) {
    const int c = (ci + rot) & 31;
    if (ci + 1 < NCHUNK) issue((ci + 1 + rot) & 31);   // loads hide under compute
    const unsigned char* base = lds + (ci & 1) * CHUNK_B;
    #pragma unroll
    for (int nt = 0; nt < 2; ++nt) {
      f32x4 aA0 = {0,0,0,0}, aB0 = {0,0,0,0}, aC0 = {0,0,0,0};
      f32x4 aA1 = {0,0,0,0}, aB1 = {0,0,0,0}, aC1 = {0,0,0,0};
      const int cil = nt * 16 + mrow;
      #pragma unroll
      for (int ks = 0; ks < 8; ++ks) {
        const int p = ks * 4 + kq;
        short8 bh = *(const short8*)(base + (p * NC + cil) * 16);
        short8 bl = *(const short8*)(base + 16384 + (p * NC + cil) * 16);
        aA0 = __builtin_amdgcn_mfma_f32_16x16x32_bf16(aH0[ks], bh, aA0, 0, 0, 0);
        aA1 = __builtin_amdgcn_mfma_f32_16x16x32_bf16(aH1[ks], bh, aA1, 0, 0, 0);
        aB0 = __builtin_amdgcn_mfma_f32_16x16x32_bf16(aL0[ks], bh, aB0, 0, 0, 0);
        aB1 = __builtin_amdgcn_mfma_f32_16x16x32_bf16(aL1[ks], bh, aB1, 0, 0, 0);
        aC0 = __builtin_amdgcn_mfma_f32_16x16x32_bf16(aH0[ks], bl, aC0, 0, 0, 0);
        aC1 = __builtin_amdgcn_mfma_f32_16x16x32_bf16(aH1[ks], bl, aC1, 0, 0, 0);
      }
      const int code = c * NC + nt * 16 + mrow;
      const float en = enp[code];
      #pragma unroll
      for (int r = 0; r < 4; ++r) {
        float d0 = aA0[r] + aB0[r] + aC0[r];
        float s0 = fmaf(-2.0f, d0, en);
        if (s0 < best0[r] || (s0 == best0[r] && code < bidx0[r])) {
          best0[r] = s0; bidx0[r] = code;
        }
        float d1 = aA1[r] + aB1[r] + aC1[r];
        float s1 = fmaf(-2.0f, d1, en);
        if (s1 < best1[r] || (s1 == best1[r] && code < bidx1[r])) {
          best1[r] = s1; bidx1[r] = code;
        }
      }
    }
    __syncthreads();                      // all waves done reading buf[ci&1]
    if (ci + 1 < NCHUNK) {
      commit((ci + 1) & 1);
      __syncthreads();                    // ds_writes visible (lgkm drained)
    }
  }

  // cross-lane argmin over the 16-lane code field, lowest-idx tie-break
  #pragma unroll
  for (int r = 0; r < 4; ++r) {
    float v = best0[r]; int ix = bidx0[r];
    #pragma unroll
    for (int o = 1; o < 16; o <<= 1) {
      float v2 = __shfl_xor(v, o); int x2 = __shfl_xor(ix, o);
      if (v2 < v || (v2 == v && x2 < ix)) { v = v2; ix = x2; }
    }
    if (mrow == 0) s_idx[w * 32 + kq * 4 + r] = ix;
    float u = best1[r]; int iy = bidx1[r];
    #pragma unroll
    for (int o = 1; o < 16; o <<= 1) {
      float u2 = __shfl_xor(u, o); int y2 = __shfl_xor(iy, o);
      if (u2 < u || (u2 == u && y2 < iy)) { u = u2; iy = y2; }
    }
    if (mrow == 0) s_idx[w * 32 + 16 + kq * 4 + r] = iy;
  }
  __syncthreads();

  if (tid < BM) {
    int ix = s_idx[tid];
    out[IDX_OFF + row0 + tid] = (float)ix;
    atomicAdd(&((unsigned*)((char*)wsf + WS_CNT_B))[ix], 1u);
  }

  // ---- fused epilogue: z_q (float4), loss, nea scatter atomics
  float lacc = 0.0f;
  const int rhalf = tid >> 6;       // 0/1
  const int c4    = tid & 63;       // float4 column
  for (int rr = 0; rr < BM / 2; ++rr) {
    int r  = rr * 2 + rhalf;
    int ix = s_idx[r];
    long zo = (long)(row0 + r) * CODE_DIM + c4 * 4;
    long eo = (long)ix * CODE_DIM + c4 * 4;
    float4 x4 = *(const float4*)&z[zo];
    float4 e4 = *(const float4*)&emb[eo];
    float dx = e4.x - x4.x, dy = e4.y - x4.y, dz = e4.z - x4.z, dw = e4.w - x4.w;
    float4 q = {x4.x + dx, x4.y + dy, x4.z + dz, x4.w + dw};
    *(float4*)&out[ZQ_OFF + zo] = q;
    lacc += dx * dx + dy * dy + dz * dz + dw * dw;
    atomicAdd(&out[NEA_OFF + eo + 0], x4.x);
    atomicAdd(&out[NEA_OFF + eo + 1], x4.y);
    atomicAdd(&out[NEA_OFF + eo + 2], x4.z);
    atomicAdd(&out[NEA_OFF + eo + 3], x4.w);
  }
  #pragma unroll
  for (int o = 32; o >= 1; o >>= 1) lacc += __shfl_xor(lacc, o);
  if (l == 0) s_l[w] = lacc;
  __syncthreads();
  if (tid == 0) atomicAdd(&out[LOSS_OFF], (s_l[0] + s_l[1]) * LOSS_SCALE);
}

// ---------------------------------------------------------------- K2: cs EMA + n
__global__ void k_fin1(const float* __restrict__ cs_in, float* __restrict__ out,
                       float* __restrict__ wsf) {
  char* wsb = (char*)wsf;
  const int t = threadIdx.x;  // 1024
  unsigned cnt = ((unsigned*)(wsb + WS_CNT_B))[t];
  float ncs = EMA * cs_in[t] + ONE_M_EMA * (float)cnt;
  out[CS_OFF + t] = ncs;
  float v = ncs;
  #pragma unroll
  for (int o = 32; o >= 1; o >>= 1) v += __shfl_xor(v, o);
  __shared__ float ns[16];
  if ((t & 63) == 0) ns[t >> 6] = v;
  __syncthreads();
  if (t == 0) {
    float n = 0.0f;
    #pragma unroll
    for (int k = 0; k < 16; ++k) n += ns[k];
    *((float*)(wsb + WS_N_B)) = n;
  }
}

// ---------------------------------------------------------------- K3: finalize nea/norm
__global__ void k_fin2(const float* __restrict__ ea, float* __restrict__ out,
                       const float* __restrict__ wsf) {
  const char* wsb = (const char*)wsf;
  const int k = blockIdx.x, d = threadIdx.x;
  __shared__ float s_cs;
  if (d == 0) {
    float n   = *((const float*)(wsb + WS_N_B));
    float ncs = out[CS_OFF + k];
    float cs  = (ncs + EPSF) / (n + (float)NUM_CODES * EPSF) * n;
    s_cs = fmaxf(cs, EPSF);
  }
  __syncthreads();
  long o = (long)k * CODE_DIM + d;
  float esum = out[NEA_OFF + o];
  float nea  = EMA * ea[o] + ONE_M_EMA * esum;
  out[NEA_OFF + o] = nea;
  out[NORM_OFF + o] = nea / s_cs;
}

// ---------------------------------------------------------------- launch
extern "C" void kernel_launch(void* const* d_in, const int* in_sizes, int n_in,
                              void* d_out, int out_size, void* d_ws, size_t ws_size,
                              hipStream_t stream) {
  const float* z   = (const float*)d_in[0];
  const float* emb = (const float*)d_in[1];
  const float* cs  = (const float*)d_in[2];
  const float* ea  = (const float*)d_in[3];
  float* out = (float*)d_out;
  float* wsf = (float*)d_ws;

  hipLaunchKernelGGL(k_setup, dim3(NUM_CODES), dim3(256), 0, stream, emb, out, wsf);
  hipLaunchKernelGGL(k_main,  dim3(N_ROWS / BM), dim3(128), 0, stream, z, emb, wsf, out);
  hipLaunchKernelGGL(k_fin1,  dim3(1), dim3(1024), 0, stream, cs, out, wsf);
  hipLaunchKernelGGL(k_fin2,  dim3(NUM_CODES), dim3(CODE_DIM), 0, stream, ea, out, wsf);
}

// Round 7
// 167.118 us; speedup vs baseline: 2.6682x; 2.6682x over previous
//
#include <hip/hip_runtime.h>

#define NUM_CODES 1024
#define CODE_DIM  256
#define N_ROWS    32768

// output layout (floats)
#define ZQ_OFF    0
#define LOSS_OFF  8388608
#define IDX_OFF   8388609
#define CS_OFF    8421377
#define NEA_OFF   8422401
#define NORM_OFF  8684545
// argmin keys (u64) parked in the NORM region (8B-aligned), overwritten by k_fin2
#define KEY_OFF   (NORM_OFF + 1)

#define EMA       0.99f
#define ONE_M_EMA 0.01f
#define EPSF      1e-6f
#define LOSS_SCALE (0.25f / 8388608.0f)

// ws layout (bytes)
#define WS_N_B      0
#define WS_ENORM_B  64
#define WS_CNT_B    (WS_ENORM_B + 4096)
#define WS_EH_B     (WS_CNT_B + 4096)     // 512 KB E hi frag-major [plane][code][8]
#define WS_EL_B     (WS_EH_B + 524288)    // 512 KB E lo

typedef __attribute__((ext_vector_type(8))) short short8;
typedef __attribute__((ext_vector_type(4))) float f32x4;

__device__ __forceinline__ unsigned short f2bf(float x) {
  union { float f; unsigned u; } v; v.f = x;
  unsigned r = v.u + 0x7fffu + ((v.u >> 16) & 1u);
  return (unsigned short)(r >> 16);
}
__device__ __forceinline__ float bf2f(unsigned short b) {
  union { unsigned u; float f; } v; v.u = ((unsigned)b) << 16;
  return v.f;
}
__device__ __forceinline__ unsigned long long packkey(float s, int code) {
  unsigned u = __float_as_uint(s);
  u = (u & 0x80000000u) ? ~u : (u | 0x80000000u);   // monotone total order on f32
  return ((unsigned long long)u << 32) | (unsigned)code;
}

typedef const __attribute__((address_space(1))) unsigned char* gas_t;
typedef __attribute__((address_space(3))) unsigned char* las_t;
__device__ __forceinline__ void gl_lds16(const void* g, void* l) {
  __builtin_amdgcn_global_load_lds((gas_t)g, (las_t)l, 16, 0, 0);
}

// ---------------------------------------------------------------- K0: setup
__global__ void k_setup(const float* __restrict__ emb, float* __restrict__ out,
                        float* __restrict__ wsf) {
  const int b = blockIdx.x, t = threadIdx.x;
  char* wsb = (char*)wsf;
  out[NEA_OFF + (long)b * 256 + t] = 0.0f;            // zero nea accumulators
  if (b < 4) ((unsigned*)(wsb + WS_CNT_B))[b * 256 + t] = 0u;
  if (b < 128) ((unsigned long long*)(out + KEY_OFF))[b * 256 + t] = ~0ull;
  if (b == 0 && t == 0) out[LOSS_OFF] = 0.0f;

  float x = emb[(long)b * CODE_DIM + t];
  unsigned short hb = f2bf(x);
  unsigned short lb = f2bf(x - bf2f(hb));
  unsigned short* eh = (unsigned short*)(wsb + WS_EH_B);
  unsigned short* el = (unsigned short*)(wsb + WS_EL_B);
  int p = t >> 3, j = t & 7;
  long eo = ((long)p * NUM_CODES + b) * 8 + j;
  eh[eo] = hb; el[eo] = lb;
  float v = x * x;
  #pragma unroll
  for (int o = 32; o >= 1; o >>= 1) v += __shfl_xor(v, o);
  __shared__ float s[4];
  if ((t & 63) == 0) s[t >> 6] = v;
  __syncthreads();
  if (t == 0) ((float*)(wsb + WS_ENORM_B))[b] = s[0] + s[1] + s[2] + s[3];
}

// ---------------------------------------------------------------- K1: main
// 256 thr (4 waves x 32 rows = 128 rows/block), 2-way code split (512 codes/block),
// counted-vmcnt pipeline (depth 2, raw s_barrier), u64 atomicMin argmin merge.
#define BMROW    128
#define NC       16
#define NCHUNK   32
#define CHUNK_B  16384       // hi 8KB + lo 8KB
#define NBUF     4

__launch_bounds__(256, 2)
__global__ void k_main(const float* __restrict__ z, const float* __restrict__ wsf,
                       float* __restrict__ out) {
  __shared__ __align__(16) unsigned char bufs[NBUF * CHUNK_B];
  __shared__ float lds_en[512];

  const char* wsb = (const char*)wsf;
  const int tid = threadIdx.x;
  const int w = tid >> 6, l = tid & 63;
  const int mrow = l & 15, kq = l >> 4;
  const int rowblk = blockIdx.x >> 1;
  const int cbase  = (blockIdx.x & 1) * 512;
  const int row0 = rowblk * BMROW;
  const int rot = rowblk & 31;

  // ---- A: 32 rows per wave (2 mtiles), hi/lo bf16 fragments in registers
  short8 aH0[8], aL0[8], aH1[8], aL1[8];
  {
    const float* zr0 = z + (long)(row0 + w * 32 + mrow) * CODE_DIM + kq * 8;
    const float* zr1 = zr0 + 16 * CODE_DIM;
    #pragma unroll
    for (int ks = 0; ks < 8; ++ks) {
      float4 f0 = *(const float4*)(zr0 + ks * 32);
      float4 f1 = *(const float4*)(zr0 + ks * 32 + 4);
      float4 g0 = *(const float4*)(zr1 + ks * 32);
      float4 g1 = *(const float4*)(zr1 + ks * 32 + 4);
      float xs[8] = {f0.x, f0.y, f0.z, f0.w, f1.x, f1.y, f1.z, f1.w};
      float ys[8] = {g0.x, g0.y, g0.z, g0.w, g1.x, g1.y, g1.z, g1.w};
      #pragma unroll
      for (int j = 0; j < 8; ++j) {
        unsigned short hb = f2bf(xs[j]);
        aH0[ks][j] = (short)hb; aL0[ks][j] = (short)f2bf(xs[j] - bf2f(hb));
        unsigned short hc = f2bf(ys[j]);
        aH1[ks][j] = (short)hc; aL1[ks][j] = (short)f2bf(ys[j] - bf2f(hc));
      }
    }
  }
  // enorm slice for my 512 codes -> LDS
  {
    const float* enp = (const float*)(wsb + WS_ENORM_B);
    lds_en[tid] = enp[cbase + tid];
    lds_en[256 + tid] = enp[cbase + 256 + tid];
  }
  __syncthreads();   // prologue drain: A-loads consumed, en visible

  auto issue = [&](int c_eff, int buf) {
    #pragma unroll
    for (int it = 0; it < 4; ++it) {
      int d = (it * 256 + tid) * 16;     // 0..16368
      int s = d >> 13;                   // 0 = hi, 1 = lo
      int d2 = d & 8191;
      int p = d2 >> 8;                   // plane 0..31 (256B = 16 codes x 16B)
      int in_ = d2 & 255;
      const char* src = wsb + (s ? WS_EL_B : WS_EH_B) + p * 16384
                        + (cbase + c_eff * 16) * 16 + in_;
      gl_lds16(src, (void*)(bufs + buf * CHUNK_B + d));
    }
  };

  float best0[4], best1[4]; int b0[4], b1[4];
  #pragma unroll
  for (int r = 0; r < 4; ++r) {
    best0[r] = 3.0e38f; b0[r] = 0x7fffffff;
    best1[r] = 3.0e38f; b1[r] = 0x7fffffff;
  }

  issue(rot, 0);
  issue((1 + rot) & 31, 1);

  for (int ci = 0; ci < NCHUNK; ++ci) {
    // counted wait: allow next chunk's 4 loads to stay in flight across the barrier
    if (ci < NCHUNK - 1) { asm volatile("s_waitcnt vmcnt(4)" ::: "memory"); }
    else                 { asm volatile("s_waitcnt vmcnt(0)" ::: "memory"); }
    __builtin_amdgcn_sched_barrier(0);
    __builtin_amdgcn_s_barrier();
    if (ci + 2 < NCHUNK) issue((ci + 2 + rot) & 31, (ci + 2) & 3);
    __builtin_amdgcn_sched_barrier(0);

    const unsigned char* base = bufs + (ci & 3) * CHUNK_B;
    const int c_eff = (ci + rot) & 31;
    f32x4 aA0 = {0,0,0,0}, aB0 = {0,0,0,0}, aC0 = {0,0,0,0};
    f32x4 aA1 = {0,0,0,0}, aB1 = {0,0,0,0}, aC1 = {0,0,0,0};
    #pragma unroll
    for (int ks = 0; ks < 8; ++ks) {
      const int p = ks * 4 + kq;
      short8 bh = *(const short8*)(base + (p * NC + mrow) * 16);
      short8 bl = *(const short8*)(base + 8192 + (p * NC + mrow) * 16);
      aA0 = __builtin_amdgcn_mfma_f32_16x16x32_bf16(aH0[ks], bh, aA0, 0, 0, 0);
      aA1 = __builtin_amdgcn_mfma_f32_16x16x32_bf16(aH1[ks], bh, aA1, 0, 0, 0);
      aB0 = __builtin_amdgcn_mfma_f32_16x16x32_bf16(aL0[ks], bh, aB0, 0, 0, 0);
      aB1 = __builtin_amdgcn_mfma_f32_16x16x32_bf16(aL1[ks], bh, aB1, 0, 0, 0);
      aC0 = __builtin_amdgcn_mfma_f32_16x16x32_bf16(aH0[ks], bl, aC0, 0, 0, 0);
      aC1 = __builtin_amdgcn_mfma_f32_16x16x32_bf16(aH1[ks], bl, aC1, 0, 0, 0);
    }
    const int lc = c_eff * NC + mrow;
    const float en = lds_en[lc];
    const int gcode = cbase + lc;
    #pragma unroll
    for (int r = 0; r < 4; ++r) {
      float d0 = aA0[r] + aB0[r] + aC0[r];
      float s0 = fmaf(-2.0f, d0, en);
      if (s0 < best0[r] || (s0 == best0[r] && gcode < b0[r])) { best0[r] = s0; b0[r] = gcode; }
      float d1 = aA1[r] + aB1[r] + aC1[r];
      float s1 = fmaf(-2.0f, d1, en);
      if (s1 < best1[r] || (s1 == best1[r] && gcode < b1[r])) { best1[r] = s1; b1[r] = gcode; }
    }
  }

  // packed cross-lane argmin over the 16-lane code field, then global u64 min-merge
  unsigned long long* keys = (unsigned long long*)(out + KEY_OFF);
  #pragma unroll
  for (int r = 0; r < 4; ++r) {
    unsigned long long k0 = packkey(best0[r], b0[r]);
    unsigned long long k1 = packkey(best1[r], b1[r]);
    #pragma unroll
    for (int o = 1; o < 16; o <<= 1) {
      unsigned long long t0 = __shfl_xor(k0, o); if (t0 < k0) k0 = t0;
      unsigned long long t1 = __shfl_xor(k1, o); if (t1 < k1) k1 = t1;
    }
    if (mrow == 0) {
      atomicMin(&keys[row0 + w * 32 + kq * 4 + r],      k0);
      atomicMin(&keys[row0 + w * 32 + 16 + kq * 4 + r], k1);
    }
  }
}

// ---------------------------------------------------------------- K2: epilogue
// idx, counts, z_q, loss, nea scatter (one atomic per lane per row — round-3 pattern)
__launch_bounds__(256)
__global__ void k_epi(const float* __restrict__ z, const float* __restrict__ emb,
                      float* __restrict__ out, float* __restrict__ wsf) {
  __shared__ int s_idx[128];
  __shared__ float s_l[4];
  const int tid = threadIdx.x;
  const int row0 = blockIdx.x * 128;
  unsigned long long* keys = (unsigned long long*)(out + KEY_OFF);
  if (tid < 128) {
    int ix = (int)(unsigned)(keys[row0 + tid] & 0xffffffffull);
    s_idx[tid] = ix;
    out[IDX_OFF + row0 + tid] = (float)ix;
    atomicAdd(&((unsigned*)((char*)wsf + WS_CNT_B))[ix], 1u);
  }
  __syncthreads();
  float lacc = 0.0f;
  for (int r = 0; r < 128; ++r) {
    int ix = s_idx[r];
    long zo = (long)(row0 + r) * CODE_DIM + tid;
    float x = z[zo];
    float e = emb[(long)ix * CODE_DIM + tid];
    float d = e - x;
    out[ZQ_OFF + zo] = x + d;            // straight-through, matches ref rounding
    lacc += d * d;
    atomicAdd(&out[NEA_OFF + (long)ix * CODE_DIM + tid], x);
  }
  #pragma unroll
  for (int o = 32; o >= 1; o >>= 1) lacc += __shfl_xor(lacc, o);
  if ((tid & 63) == 0) s_l[tid >> 6] = lacc;
  __syncthreads();
  if (tid == 0)
    atomicAdd(&out[LOSS_OFF], (s_l[0] + s_l[1] + s_l[2] + s_l[3]) * LOSS_SCALE);
}

// ---------------------------------------------------------------- K3: cs EMA + n
__global__ void k_fin1(const float* __restrict__ cs_in, float* __restrict__ out,
                       float* __restrict__ wsf) {
  char* wsb = (char*)wsf;
  const int t = threadIdx.x;  // 1024
  unsigned cnt = ((unsigned*)(wsb + WS_CNT_B))[t];
  float ncs = EMA * cs_in[t] + ONE_M_EMA * (float)cnt;
  out[CS_OFF + t] = ncs;
  float v = ncs;
  #pragma unroll
  for (int o = 32; o >= 1; o >>= 1) v += __shfl_xor(v, o);
  __shared__ float ns[16];
  if ((t & 63) == 0) ns[t >> 6] = v;
  __syncthreads();
  if (t == 0) {
    float n = 0.0f;
    #pragma unroll
    for (int k = 0; k < 16; ++k) n += ns[k];
    *((float*)(wsb + WS_N_B)) = n;
  }
}

// ---------------------------------------------------------------- K4: finalize (overwrites key area)
__global__ void k_fin2(const float* __restrict__ ea, float* __restrict__ out,
                       const float* __restrict__ wsf) {
  const char* wsb = (const char*)wsf;
  const int k = blockIdx.x, d = threadIdx.x;
  __shared__ float s_cs;
  if (d == 0) {
    float n   = *((const float*)(wsb + WS_N_B));
    float ncs = out[CS_OFF + k];
    float cs  = (ncs + EPSF) / (n + (float)NUM_CODES * EPSF) * n;
    s_cs = fmaxf(cs, EPSF);
  }
  __syncthreads();
  long o = (long)k * CODE_DIM + d;
  float esum = out[NEA_OFF + o];
  float nea  = EMA * ea[o] + ONE_M_EMA * esum;
  out[NEA_OFF + o] = nea;
  out[NORM_OFF + o] = nea / s_cs;
}

// ---------------------------------------------------------------- launch
extern "C" void kernel_launch(void* const* d_in, const int* in_sizes, int n_in,
                              void* d_out, int out_size, void* d_ws, size_t ws_size,
                              hipStream_t stream) {
  const float* z   = (const float*)d_in[0];
  const float* emb = (const float*)d_in[1];
  const float* cs  = (const float*)d_in[2];
  const float* ea  = (const float*)d_in[3];
  float* out = (float*)d_out;
  float* wsf = (float*)d_ws;

  hipLaunchKernelGGL(k_setup, dim3(NUM_CODES), dim3(256), 0, stream, emb, out, wsf);
  hipLaunchKernelGGL(k_main,  dim3(2 * N_ROWS / BMROW), dim3(256), 0, stream, z, wsf, out);
  hipLaunchKernelGGL(k_epi,   dim3(N_ROWS / 128), dim3(256), 0, stream, z, emb, out, wsf);
  hipLaunchKernelGGL(k_fin1,  dim3(1), dim3(1024), 0, stream, cs, out, wsf);
  hipLaunchKernelGGL(k_fin2,  dim3(NUM_CODES), dim3(CODE_DIM), 0, stream, ea, out, wsf);
}

// Round 8
// 158.655 us; speedup vs baseline: 2.8105x; 1.0533x over previous
//
#include <hip/hip_runtime.h>

#define NUM_CODES 1024
#define CODE_DIM  256
#define N_ROWS    32768

// output layout (floats)
#define ZQ_OFF    0
#define LOSS_OFF  8388608
#define IDX_OFF   8388609
#define CS_OFF    8421377
#define NEA_OFF   8422401
#define NORM_OFF  8684545
// argmin keys (u64) parked in the NORM region (8B-aligned), overwritten by k_fin2
#define KEY_OFF   (NORM_OFF + 1)

#define EMA       0.99f
#define ONE_M_EMA 0.01f
#define EPSF      1e-6f
#define LOSS_SCALE (0.25f / 8388608.0f)

// ws layout (bytes)
#define WS_N_B      0
#define WS_ENORM_B  64
#define WS_CNT_B    (WS_ENORM_B + 4096)
#define WS_EH_B     (WS_CNT_B + 4096)     // 512 KB E hi frag-major [plane][code][8]
#define WS_EL_B     (WS_EH_B + 524288)    // 512 KB E lo

typedef __attribute__((ext_vector_type(8))) short short8;
typedef __attribute__((ext_vector_type(4))) float f32x4;

__device__ __forceinline__ unsigned short f2bf(float x) {
  union { float f; unsigned u; } v; v.f = x;
  unsigned r = v.u + 0x7fffu + ((v.u >> 16) & 1u);
  return (unsigned short)(r >> 16);
}
__device__ __forceinline__ float bf2f(unsigned short b) {
  union { unsigned u; float f; } v; v.u = ((unsigned)b) << 16;
  return v.f;
}
__device__ __forceinline__ unsigned long long packkey(float s, int code) {
  unsigned u = __float_as_uint(s);
  u = (u & 0x80000000u) ? ~u : (u | 0x80000000u);   // monotone total order on f32
  return ((unsigned long long)u << 32) | (unsigned)code;
}

typedef const __attribute__((address_space(1))) unsigned char* gas_t;
typedef __attribute__((address_space(3))) unsigned char* las_t;
__device__ __forceinline__ void gl_lds16(const void* g, void* l) {
  __builtin_amdgcn_global_load_lds((gas_t)g, (las_t)l, 16, 0, 0);
}

// ---------------------------------------------------------------- K0: setup
__global__ void k_setup(const float* __restrict__ emb, float* __restrict__ out,
                        float* __restrict__ wsf) {
  const int b = blockIdx.x, t = threadIdx.x;
  char* wsb = (char*)wsf;
  out[NEA_OFF + (long)b * 256 + t] = 0.0f;            // zero nea accumulators
  if (b < 4) ((unsigned*)(wsb + WS_CNT_B))[b * 256 + t] = 0u;
  if (b < 128) ((unsigned long long*)(out + KEY_OFF))[b * 256 + t] = ~0ull;
  if (b == 0 && t == 0) out[LOSS_OFF] = 0.0f;

  float x = emb[(long)b * CODE_DIM + t];
  unsigned short hb = f2bf(x);
  unsigned short lb = f2bf(x - bf2f(hb));
  unsigned short* eh = (unsigned short*)(wsb + WS_EH_B);
  unsigned short* el = (unsigned short*)(wsb + WS_EL_B);
  int p = t >> 3, j = t & 7;
  long eo = ((long)p * NUM_CODES + b) * 8 + j;
  eh[eo] = hb; el[eo] = lb;
  float v = x * x;
  #pragma unroll
  for (int o = 32; o >= 1; o >>= 1) v += __shfl_xor(v, o);
  __shared__ float s[4];
  if ((t & 63) == 0) s[t >> 6] = v;
  __syncthreads();
  if (t == 0) ((float*)(wsb + WS_ENORM_B))[b] = s[0] + s[1] + s[2] + s[3];
}

// ---------------------------------------------------------------- K1: main
// 256 thr (4 waves x 32 rows = 128 rows/block), 2-way code split (512 codes/block),
// counted-vmcnt pipeline (depth 2, raw s_barrier), u64 atomicMin argmin merge.
#define BMROW    128
#define NC       16
#define NCHUNK   32
#define CHUNK_B  16384       // hi 8KB + lo 8KB
#define NBUF     4

__launch_bounds__(256, 2)
__global__ void k_main(const float* __restrict__ z, const float* __restrict__ wsf,
                       float* __restrict__ out) {
  __shared__ __align__(16) unsigned char bufs[NBUF * CHUNK_B];
  __shared__ float lds_en[512];

  const char* wsb = (const char*)wsf;
  const int tid = threadIdx.x;
  const int w = tid >> 6, l = tid & 63;
  const int mrow = l & 15, kq = l >> 4;
  const int rowblk = blockIdx.x >> 1;
  const int cbase  = (blockIdx.x & 1) * 512;
  const int row0 = rowblk * BMROW;
  const int rot = rowblk & 31;

  // ---- A: 32 rows per wave (2 mtiles), hi/lo bf16 fragments in registers
  short8 aH0[8], aL0[8], aH1[8], aL1[8];
  {
    const float* zr0 = z + (long)(row0 + w * 32 + mrow) * CODE_DIM + kq * 8;
    const float* zr1 = zr0 + 16 * CODE_DIM;
    #pragma unroll
    for (int ks = 0; ks < 8; ++ks) {
      float4 f0 = *(const float4*)(zr0 + ks * 32);
      float4 f1 = *(const float4*)(zr0 + ks * 32 + 4);
      float4 g0 = *(const float4*)(zr1 + ks * 32);
      float4 g1 = *(const float4*)(zr1 + ks * 32 + 4);
      float xs[8] = {f0.x, f0.y, f0.z, f0.w, f1.x, f1.y, f1.z, f1.w};
      float ys[8] = {g0.x, g0.y, g0.z, g0.w, g1.x, g1.y, g1.z, g1.w};
      #pragma unroll
      for (int j = 0; j < 8; ++j) {
        unsigned short hb = f2bf(xs[j]);
        aH0[ks][j] = (short)hb; aL0[ks][j] = (short)f2bf(xs[j] - bf2f(hb));
        unsigned short hc = f2bf(ys[j]);
        aH1[ks][j] = (short)hc; aL1[ks][j] = (short)f2bf(ys[j] - bf2f(hc));
      }
    }
  }
  // enorm slice for my 512 codes -> LDS
  {
    const float* enp = (const float*)(wsb + WS_ENORM_B);
    lds_en[tid] = enp[cbase + tid];
    lds_en[256 + tid] = enp[cbase + 256 + tid];
  }
  __syncthreads();   // prologue drain: A-loads consumed, en visible

  auto issue = [&](int c_eff, int buf) {
    #pragma unroll
    for (int it = 0; it < 4; ++it) {
      int d = (it * 256 + tid) * 16;     // 0..16368
      int s = d >> 13;                   // 0 = hi, 1 = lo
      int d2 = d & 8191;
      int p = d2 >> 8;                   // plane 0..31 (256B = 16 codes x 16B)
      int in_ = d2 & 255;
      const char* src = wsb + (s ? WS_EL_B : WS_EH_B) + p * 16384
                        + (cbase + c_eff * 16) * 16 + in_;
      gl_lds16(src, (void*)(bufs + buf * CHUNK_B + d));
    }
  };

  float best0[4], best1[4]; int b0[4], b1[4];
  #pragma unroll
  for (int r = 0; r < 4; ++r) {
    best0[r] = 3.0e38f; b0[r] = 0x7fffffff;
    best1[r] = 3.0e38f; b1[r] = 0x7fffffff;
  }

  issue(rot, 0);
  issue((1 + rot) & 31, 1);

  for (int ci = 0; ci < NCHUNK; ++ci) {
    // counted wait: allow next chunk's 4 loads to stay in flight across the barrier
    if (ci < NCHUNK - 1) { asm volatile("s_waitcnt vmcnt(4)" ::: "memory"); }
    else                 { asm volatile("s_waitcnt vmcnt(0)" ::: "memory"); }
    __builtin_amdgcn_sched_barrier(0);
    __builtin_amdgcn_s_barrier();
    if (ci + 2 < NCHUNK) issue((ci + 2 + rot) & 31, (ci + 2) & 3);
    __builtin_amdgcn_sched_barrier(0);

    const unsigned char* base = bufs + (ci & 3) * CHUNK_B;
    const int c_eff = (ci + rot) & 31;
    f32x4 aA0 = {0,0,0,0}, aB0 = {0,0,0,0}, aC0 = {0,0,0,0};
    f32x4 aA1 = {0,0,0,0}, aB1 = {0,0,0,0}, aC1 = {0,0,0,0};
    #pragma unroll
    for (int ks = 0; ks < 8; ++ks) {
      const int p = ks * 4 + kq;
      short8 bh = *(const short8*)(base + (p * NC + mrow) * 16);
      short8 bl = *(const short8*)(base + 8192 + (p * NC + mrow) * 16);
      aA0 = __builtin_amdgcn_mfma_f32_16x16x32_bf16(aH0[ks], bh, aA0, 0, 0, 0);
      aA1 = __builtin_amdgcn_mfma_f32_16x16x32_bf16(aH1[ks], bh, aA1, 0, 0, 0);
      aB0 = __builtin_amdgcn_mfma_f32_16x16x32_bf16(aL0[ks], bh, aB0, 0, 0, 0);
      aB1 = __builtin_amdgcn_mfma_f32_16x16x32_bf16(aL1[ks], bh, aB1, 0, 0, 0);
      aC0 = __builtin_amdgcn_mfma_f32_16x16x32_bf16(aH0[ks], bl, aC0, 0, 0, 0);
      aC1 = __builtin_amdgcn_mfma_f32_16x16x32_bf16(aH1[ks], bl, aC1, 0, 0, 0);
    }
    const int lc = c_eff * NC + mrow;
    const float en = lds_en[lc];
    const int gcode = cbase + lc;
    #pragma unroll
    for (int r = 0; r < 4; ++r) {
      float d0 = aA0[r] + aB0[r] + aC0[r];
      float s0 = fmaf(-2.0f, d0, en);
      if (s0 < best0[r] || (s0 == best0[r] && gcode < b0[r])) { best0[r] = s0; b0[r] = gcode; }
      float d1 = aA1[r] + aB1[r] + aC1[r];
      float s1 = fmaf(-2.0f, d1, en);
      if (s1 < best1[r] || (s1 == best1[r] && gcode < b1[r])) { best1[r] = s1; b1[r] = gcode; }
    }
  }

  // packed cross-lane argmin over the 16-lane code field, then global u64 min-merge
  unsigned long long* keys = (unsigned long long*)(out + KEY_OFF);
  #pragma unroll
  for (int r = 0; r < 4; ++r) {
    unsigned long long k0 = packkey(best0[r], b0[r]);
    unsigned long long k1 = packkey(best1[r], b1[r]);
    #pragma unroll
    for (int o = 1; o < 16; o <<= 1) {
      unsigned long long t0 = __shfl_xor(k0, o); if (t0 < k0) k0 = t0;
      unsigned long long t1 = __shfl_xor(k1, o); if (t1 < k1) k1 = t1;
    }
    if (mrow == 0) {
      atomicMin(&keys[row0 + w * 32 + kq * 4 + r],      k0);
      atomicMin(&keys[row0 + w * 32 + 16 + kq * 4 + r], k1);
    }
  }
}

// ---------------------------------------------------------------- K2: epilogue
// 32 rows/block x 1024 blocks; idx, counts, z_q, loss, nea scatter
// (one atomic per lane per row — round-2/3 pattern; unroll 4 for MLP)
#define EPI_ROWS 32

__launch_bounds__(256)
__global__ void k_epi(const float* __restrict__ z, const float* __restrict__ emb,
                      float* __restrict__ out, float* __restrict__ wsf) {
  __shared__ int s_idx[EPI_ROWS];
  __shared__ float s_l[4];
  const int tid = threadIdx.x;
  const int row0 = blockIdx.x * EPI_ROWS;
  unsigned long long* keys = (unsigned long long*)(out + KEY_OFF);
  if (tid < EPI_ROWS) {
    int ix = (int)(unsigned)(keys[row0 + tid] & 0xffffffffull);
    s_idx[tid] = ix;
    out[IDX_OFF + row0 + tid] = (float)ix;
    atomicAdd(&((unsigned*)((char*)wsf + WS_CNT_B))[ix], 1u);
  }
  __syncthreads();
  float lacc = 0.0f;
  #pragma unroll 4
  for (int r = 0; r < EPI_ROWS; ++r) {
    int ix = s_idx[r];
    long zo = (long)(row0 + r) * CODE_DIM + tid;
    float x = z[zo];
    float e = emb[(long)ix * CODE_DIM + tid];
    float d = e - x;
    out[ZQ_OFF + zo] = x + d;            // straight-through, matches ref rounding
    lacc += d * d;
    atomicAdd(&out[NEA_OFF + (long)ix * CODE_DIM + tid], x);
  }
  #pragma unroll
  for (int o = 32; o >= 1; o >>= 1) lacc += __shfl_xor(lacc, o);
  if ((tid & 63) == 0) s_l[tid >> 6] = lacc;
  __syncthreads();
  if (tid == 0)
    atomicAdd(&out[LOSS_OFF], (s_l[0] + s_l[1] + s_l[2] + s_l[3]) * LOSS_SCALE);
}

// ---------------------------------------------------------------- K3: cs EMA + n
__global__ void k_fin1(const float* __restrict__ cs_in, float* __restrict__ out,
                       float* __restrict__ wsf) {
  char* wsb = (char*)wsf;
  const int t = threadIdx.x;  // 1024
  unsigned cnt = ((unsigned*)(wsb + WS_CNT_B))[t];
  float ncs = EMA * cs_in[t] + ONE_M_EMA * (float)cnt;
  out[CS_OFF + t] = ncs;
  float v = ncs;
  #pragma unroll
  for (int o = 32; o >= 1; o >>= 1) v += __shfl_xor(v, o);
  __shared__ float ns[16];
  if ((t & 63) == 0) ns[t >> 6] = v;
  __syncthreads();
  if (t == 0) {
    float n = 0.0f;
    #pragma unroll
    for (int k = 0; k < 16; ++k) n += ns[k];
    *((float*)(wsb + WS_N_B)) = n;
  }
}

// ---------------------------------------------------------------- K4: finalize (overwrites key area)
__global__ void k_fin2(const float* __restrict__ ea, float* __restrict__ out,
                       const float* __restrict__ wsf) {
  const char* wsb = (const char*)wsf;
  const int k = blockIdx.x, d = threadIdx.x;
  __shared__ float s_cs;
  if (d == 0) {
    float n   = *((const float*)(wsb + WS_N_B));
    float ncs = out[CS_OFF + k];
    float cs  = (ncs + EPSF) / (n + (float)NUM_CODES * EPSF) * n;
    s_cs = fmaxf(cs, EPSF);
  }
  __syncthreads();
  long o = (long)k * CODE_DIM + d;
  float esum = out[NEA_OFF + o];
  float nea  = EMA * ea[o] + ONE_M_EMA * esum;
  out[NEA_OFF + o] = nea;
  out[NORM_OFF + o] = nea / s_cs;
}

// ---------------------------------------------------------------- launch
extern "C" void kernel_launch(void* const* d_in, const int* in_sizes, int n_in,
                              void* d_out, int out_size, void* d_ws, size_t ws_size,
                              hipStream_t stream) {
  const float* z   = (const float*)d_in[0];
  const float* emb = (const float*)d_in[1];
  const float* cs  = (const float*)d_in[2];
  const float* ea  = (const float*)d_in[3];
  float* out = (float*)d_out;
  float* wsf = (float*)d_ws;

  hipLaunchKernelGGL(k_setup, dim3(NUM_CODES), dim3(256), 0, stream, emb, out, wsf);
  hipLaunchKernelGGL(k_main,  dim3(2 * N_ROWS / BMROW), dim3(256), 0, stream, z, wsf, out);
  hipLaunchKernelGGL(k_epi,   dim3(N_ROWS / EPI_ROWS), dim3(256), 0, stream, z, emb, out, wsf);
  hipLaunchKernelGGL(k_fin1,  dim3(1), dim3(1024), 0, stream, cs, out, wsf);
  hipLaunchKernelGGL(k_fin2,  dim3(NUM_CODES), dim3(CODE_DIM), 0, stream, ea, out, wsf);
}